// Round 1
// baseline (6035.555 us; speedup 1.0000x reference)
//
#include <hip/hip_runtime.h>
#include <hip/hip_bf16.h>

typedef unsigned short u16;
typedef __attribute__((ext_vector_type(8))) __bf16 bf16x8;
typedef __attribute__((ext_vector_type(4))) float f32x4;
typedef __attribute__((ext_vector_type(4))) unsigned short u16x4;

#define BB 8
#define SS 2048
#define DD 768
#define DFF 3072
#define NL 12
#define ROWS (BB*SS)
#define VOC 32000

__device__ __forceinline__ u16 f2bf(float f){
  union { float f; unsigned u; } v; v.f = f;
  unsigned u = v.u;
  u += 0x7FFF + ((u >> 16) & 1);
  return (u16)(u >> 16);
}

// ---------- setup kernels ----------
__global__ void k_embed(const int* __restrict__ tok, const float4* __restrict__ emb,
                        float4* __restrict__ x){
  int i = blockIdx.x*256 + threadIdx.x;
  if (i >= ROWS*192) return;
  int row = i/192, c = i - row*192;
  x[i] = emb[(long)tok[row]*192 + c];
}

__global__ void k_dftD(u16* __restrict__ out){ // [1536][768]: rows<768 cos, >=768 sin
  int i = blockIdx.x*256 + threadIdx.x;
  if (i >= 1536*768) return;
  int n = i/768, k = i - n*768;
  int nn = (n < 768) ? n : n - 768;
  int m = (nn*k) % 768;
  float a = 2.0f*(float)m/768.0f;
  out[i] = f2bf((n < 768) ? cospif(a) : sinpif(a));
}

__global__ void k_dftS(u16* __restrict__ out){ // [2048][4096]: cols<2048 cos, >=2048 -sin
  int i = blockIdx.x*256 + threadIdx.x;
  if (i >= 2048*4096) return;
  int s = i >> 12, t = i & 4095;
  int tt = (t < 2048) ? t : t - 2048;
  int m = (s*tt) & 2047;
  float a = (float)m * (2.0f/2048.0f);
  out[i] = f2bf((t < 2048) ? cospif(a) : -sinpif(a));
}

// one wave per row of 768
__global__ void k_ln(const float* __restrict__ x, const float* __restrict__ g,
                     const float* __restrict__ b, u16* __restrict__ h){
  int row = blockIdx.x*4 + (threadIdx.x >> 6);
  int lane = threadIdx.x & 63;
  const float* xr = x + (long)row*DD;
  float v[12];
  float s = 0.f;
  #pragma unroll
  for (int j = 0; j < 12; j++){ v[j] = xr[lane + j*64]; s += v[j]; }
  #pragma unroll
  for (int o = 32; o > 0; o >>= 1) s += __shfl_xor(s, o);
  float mu = s * (1.0f/768.0f);
  float q = 0.f;
  #pragma unroll
  for (int j = 0; j < 12; j++){ float d = v[j]-mu; q += d*d; }
  #pragma unroll
  for (int o = 32; o > 0; o >>= 1) q += __shfl_xor(q, o);
  float rs = rsqrtf(q * (1.0f/768.0f) + 1e-5f);
  u16* hr = h + (long)row*DD;
  #pragma unroll
  for (int j = 0; j < 12; j++){
    int e = lane + j*64;
    hr[e] = f2bf((v[j]-mu)*rs*g[e] + b[e]);
  }
}

// f32 [R][C] -> bf16 [C][R]
__global__ void k_transpose_cvt(const float* __restrict__ src, u16* __restrict__ dst,
                                int R, int C){
  __shared__ float t[32][33];
  int bx = blockIdx.x*32, by = blockIdx.y*32;
  int tx = threadIdx.x, ty = threadIdx.y;
  #pragma unroll
  for (int i = 0; i < 4; i++) t[ty+i*8][tx] = src[(long)(by+ty+i*8)*C + bx+tx];
  __syncthreads();
  #pragma unroll
  for (int i = 0; i < 4; i++) dst[(long)(bx+ty+i*8)*R + by+tx] = f2bf(t[tx][ty+i*8]);
}

#define EPI_DFT  0
#define EPI_ADDX 1
#define EPI_GELU 2

// C = A[M,K] * BT[N,K]^T ; 128x128 tile, BK=32, 4 waves (m97 structure)
template<int EPI>
__global__ __launch_bounds__(256)
void k_gemm(const u16* __restrict__ A, const u16* __restrict__ BT,
            int M, int N, int K, long aBS, long btBS, int rowOffPerZ,
            float* __restrict__ X, const float* __restrict__ bias,
            u16* __restrict__ OUT){
  __shared__ u16 sA[4096];
  __shared__ u16 sB[4096];
  const int tid  = threadIdx.x;
  const int wave = tid >> 6, lane = tid & 63;
  const int wr = (wave >> 1)*64, wc = (wave & 1)*64;
  const int bm = blockIdx.x*128, bn = blockIdx.y*128;
  const int bz = blockIdx.z;
  const u16* Ab = A + (long)bz*aBS;
  const u16* Bb = BT + (long)bz*btBS;
  const int rowOff = bz*rowOffPerZ;

  f32x4 acc[4][4] = {};

  const int ldR = tid >> 2;
  const int ldC = (tid & 3) * 8;
  const u16* aS = Ab + (long)(bm + ldR)*K + ldC;
  const u16* bS = Bb + (long)(bn + ldR)*K + ldC;
  u16* sAd = &sA[wave*512];   // wave-uniform LDS dest (HW: base + lane*16B)
  u16* sBd = &sB[wave*512];

  const int fr = lane & 15;
  const int fk = (lane >> 4) * 8;

  for (int k0 = 0; k0 < K; k0 += 32){
    __syncthreads();
    __builtin_amdgcn_global_load_lds((__attribute__((address_space(1))) void*)(aS),
                                     (__attribute__((address_space(3))) void*)(sAd), 16, 0, 0);
    __builtin_amdgcn_global_load_lds((__attribute__((address_space(1))) void*)(aS + (long)64*K),
                                     (__attribute__((address_space(3))) void*)(sAd + 2048), 16, 0, 0);
    __builtin_amdgcn_global_load_lds((__attribute__((address_space(1))) void*)(bS),
                                     (__attribute__((address_space(3))) void*)(sBd), 16, 0, 0);
    __builtin_amdgcn_global_load_lds((__attribute__((address_space(1))) void*)(bS + (long)64*K),
                                     (__attribute__((address_space(3))) void*)(sBd + 2048), 16, 0, 0);
    aS += 32; bS += 32;
    __syncthreads();
    bf16x8 af[4], bf8[4];
    #pragma unroll
    for (int m = 0; m < 4; m++) af[m]  = *(const bf16x8*)&sA[(wr + m*16 + fr)*32 + fk];
    #pragma unroll
    for (int n = 0; n < 4; n++) bf8[n] = *(const bf16x8*)&sB[(wc + n*16 + fr)*32 + fk];
    #pragma unroll
    for (int m = 0; m < 4; m++)
      #pragma unroll
      for (int n = 0; n < 4; n++)
        acc[m][n] = __builtin_amdgcn_mfma_f32_16x16x32_bf16(af[m], bf8[n], acc[m][n], 0, 0, 0);
  }

  const int er = (lane >> 4)*4, ec = lane & 15;
  #pragma unroll
  for (int m = 0; m < 4; m++){
    int r0 = bm + wr + m*16 + er;
    #pragma unroll
    for (int n = 0; n < 4; n++){
      int c = bn + wc + n*16 + ec;
      f32x4 v = acc[m][n];
      if constexpr (EPI == EPI_ADDX){
        float bv = bias ? bias[c] : 0.0f;
        #pragma unroll
        for (int r = 0; r < 4; r++)
          X[(long)(rowOff + r0 + r)*N + c] += v[r] + bv;
      } else if constexpr (EPI == EPI_GELU){
        float bv = bias[c];
        #pragma unroll
        for (int r = 0; r < 4; r++){
          float tt = v[r] + bv;
          OUT[(long)(r0 + r)*N + c] = f2bf(0.5f*tt*(1.0f + erff(tt*0.70710678118654752f)));
        }
      } else { // EPI_DFT: write transposed per batch into F[b][d][slot]
        int bb = r0 >> 11, s = r0 & 2047;
        int d, slot;
        if (c < 768){ d = c; slot = s; } else { d = c - 768; slot = 2048 + s; }
        u16x4 pk;
        #pragma unroll
        for (int r = 0; r < 4; r++) pk[r] = f2bf(v[r]);
        *(u16x4*)&OUT[((long)(bb*768 + d))*4096 + slot] = pk;
      }
    }
  }
}

__global__ void k_logits(const float* __restrict__ x, const float* __restrict__ Wout,
                         const float* __restrict__ bout, float* __restrict__ out){
  __shared__ float xl[8][768];
  int tid = threadIdx.x;
  for (int i = tid; i < 8*768; i += 256){
    int b = i/768, d = i - b*768;
    xl[b][d] = x[((long)(b*2048 + 2047))*768 + d];
  }
  __syncthreads();
  int v = blockIdx.x*256 + tid;
  float acc[8];
  float bv = bout[v];
  #pragma unroll
  for (int b = 0; b < 8; b++) acc[b] = bv;
  for (int d = 0; d < 768; d++){
    float w = Wout[(long)d*VOC + v];
    #pragma unroll
    for (int b = 0; b < 8; b++) acc[b] += xl[b][d]*w;
  }
  #pragma unroll
  for (int b = 0; b < 8; b++) out[(long)b*VOC + v] = acc[b];
}

extern "C" void kernel_launch(void* const* d_in, const int* in_sizes, int n_in,
                              void* d_out, int out_size, void* d_ws, size_t ws_size,
                              hipStream_t stream){
  const int*   tokens = (const int*)d_in[0];
  const float* embed  = (const float*)d_in[1];
  const float* ln1_g  = (const float*)d_in[2];
  const float* ln1_b  = (const float*)d_in[3];
  const float* ln2_g  = (const float*)d_in[4];
  const float* ln2_b  = (const float*)d_in[5];
  const float* W1     = (const float*)d_in[6];
  const float* b1     = (const float*)d_in[7];
  const float* W2     = (const float*)d_in[8];
  const float* b2     = (const float*)d_in[9];
  const float* Wout   = (const float*)d_in[10];
  const float* bout   = (const float*)d_in[11];
  float* out = (float*)d_out;

  char* p = (char*)d_ws;
  size_t off = 0;
  auto alloc = [&](size_t bytes)->char*{
    char* r = p + off; off += (bytes + 255) & ~(size_t)255; return r;
  };
  float* x   = (float*)alloc((size_t)ROWS*DD*4);     // f32 residual stream
  u16*   h   = (u16*)  alloc((size_t)ROWS*DD*2);     // LN output bf16
  u16*  gbuf = (u16*)  alloc((size_t)ROWS*DFF*2);    // MLP hidden; aliased as F
  u16*  dftD = (u16*)  alloc((size_t)1536*768*2);
  u16*  dftS = (u16*)  alloc((size_t)2048*4096*2);
  u16*  w1t  = (u16*)  alloc((size_t)DFF*DD*2);
  u16*  w2t  = (u16*)  alloc((size_t)DD*DFF*2);
  if (off > ws_size) return; // workspace too small -> visible as validation failure
  u16* F = gbuf;

  k_dftD<<<(1536*768+255)/256, 256, 0, stream>>>(dftD);
  k_dftS<<<(2048*4096+255)/256, 256, 0, stream>>>(dftS);
  k_embed<<<(ROWS*192+255)/256, 256, 0, stream>>>(tokens, (const float4*)embed, (float4*)x);

  for (int l = 0; l < NL; l++){
    k_ln<<<ROWS/4, 256, 0, stream>>>(x, ln1_g + l*DD, ln1_b + l*DD, h);
    // yc|ys = h @ [C_D^T | S_D^T], written transposed into F
    k_gemm<EPI_DFT><<<dim3(ROWS/128, 1536/128, 1), 256, 0, stream>>>(
        h, dftD, ROWS, 1536, 768, 0, 0, 0, nullptr, nullptr, F);
    // x += [C_S | -S_S] @ [yc ; ys]   (batched over 8)
    k_gemm<EPI_ADDX><<<dim3(2048/128, 768/128, 8), 256, 0, stream>>>(
        dftS, F, 2048, 768, 4096, 0, (long)768*4096, 2048, x, nullptr, nullptr);
    k_ln<<<ROWS/4, 256, 0, stream>>>(x, ln2_g + l*DD, ln2_b + l*DD, h);
    k_transpose_cvt<<<dim3(DFF/32, DD/32), dim3(32,8), 0, stream>>>(
        W1 + (long)l*DD*DFF, w1t, DD, DFF);
    k_transpose_cvt<<<dim3(DD/32, DFF/32), dim3(32,8), 0, stream>>>(
        W2 + (long)l*DFF*DD, w2t, DFF, DD);
    // g = gelu(h @ W1 + b1)
    k_gemm<EPI_GELU><<<dim3(ROWS/128, DFF/128, 1), 256, 0, stream>>>(
        h, w1t, ROWS, DFF, 768, 0, 0, 0, nullptr, b1 + l*DFF, gbuf);
    // x += g @ W2 + b2
    k_gemm<EPI_ADDX><<<dim3(ROWS/128, 768/128, 1), 256, 0, stream>>>(
        gbuf, w2t, ROWS, 768, 3072, 0, 0, 0, x, b2 + l*DD, nullptr);
  }
  k_logits<<<VOC/256, 256, 0, stream>>>(x, Wout, bout, out);
}

// Round 7
// 5442.535 us; speedup vs baseline: 1.1090x; 1.1090x over previous
//
#include <hip/hip_runtime.h>
#include <hip/hip_bf16.h>

typedef unsigned short u16;
typedef __attribute__((ext_vector_type(8))) __bf16 bf16x8;
typedef __attribute__((ext_vector_type(4))) float f32x4;
typedef __attribute__((ext_vector_type(4))) unsigned short u16x4;

#define BB 8
#define SS 2048
#define DD 768
#define DFF 3072
#define NL 12
#define ROWS (BB*SS)
#define VOC 32000

__device__ __forceinline__ u16 f2bf(float f){
  union { float f; unsigned u; } v; v.f = f;
  unsigned u = v.u;
  u += 0x7FFF + ((u >> 16) & 1);
  return (u16)(u >> 16);
}

// ---------- setup kernels ----------
__global__ void k_embed(const int* __restrict__ tok, const float4* __restrict__ emb,
                        float4* __restrict__ x){
  int i = blockIdx.x*256 + threadIdx.x;
  if (i >= ROWS*192) return;
  int row = i/192, c = i - row*192;
  x[i] = emb[(long)tok[row]*192 + c];
}

__global__ void k_dftD(u16* __restrict__ out){ // [1536][768]: rows<768 cos, >=768 sin
  int i = blockIdx.x*256 + threadIdx.x;
  if (i >= 1536*768) return;
  int n = i/768, k = i - n*768;
  int nn = (n < 768) ? n : n - 768;
  int m = (nn*k) % 768;
  float a = 2.0f*(float)m/768.0f;
  out[i] = f2bf((n < 768) ? cospif(a) : sinpif(a));
}

__global__ void k_dftS(u16* __restrict__ out){ // [2048][4096]: cols<2048 cos, >=2048 -sin
  int i = blockIdx.x*256 + threadIdx.x;
  if (i >= 2048*4096) return;
  int t = i >> 12, s = i & 4095;
  int ss = (s < 2048) ? s : s - 2048;
  int m = (t*ss) & 2047;
  float a = (float)m * (2.0f/2048.0f);
  out[i] = f2bf((s < 2048) ? cospif(a) : -sinpif(a));
}

// one wave per row of 768
__global__ void k_ln(const float* __restrict__ x, const float* __restrict__ g,
                     const float* __restrict__ b, u16* __restrict__ h){
  int row = blockIdx.x*4 + (threadIdx.x >> 6);
  int lane = threadIdx.x & 63;
  const float* xr = x + (long)row*DD;
  float v[12];
  float s = 0.f;
  #pragma unroll
  for (int j = 0; j < 12; j++){ v[j] = xr[lane + j*64]; s += v[j]; }
  #pragma unroll
  for (int o = 32; o > 0; o >>= 1) s += __shfl_xor(s, o);
  float mu = s * (1.0f/768.0f);
  float q = 0.f;
  #pragma unroll
  for (int j = 0; j < 12; j++){ float d = v[j]-mu; q += d*d; }
  #pragma unroll
  for (int o = 32; o > 0; o >>= 1) q += __shfl_xor(q, o);
  float rs = rsqrtf(q * (1.0f/768.0f) + 1e-5f);
  u16* hr = h + (long)row*DD;
  #pragma unroll
  for (int j = 0; j < 12; j++){
    int e = lane + j*64;
    hr[e] = f2bf((v[j]-mu)*rs*g[e] + b[e]);
  }
}

// f32 [R][C] -> bf16 [C][R]
__global__ void k_transpose_cvt(const float* __restrict__ src, u16* __restrict__ dst,
                                int R, int C){
  __shared__ float t[32][33];
  int bx = blockIdx.x*32, by = blockIdx.y*32;
  int tx = threadIdx.x, ty = threadIdx.y;
  #pragma unroll
  for (int i = 0; i < 4; i++) t[ty+i*8][tx] = src[(long)(by+ty+i*8)*C + bx+tx];
  __syncthreads();
  #pragma unroll
  for (int i = 0; i < 4; i++) dst[(long)(bx+ty+i*8)*R + by+tx] = f2bf(t[tx][ty+i*8]);
}

#define EPI_DFT  0
#define EPI_ADDX 1
#define EPI_GELU 2

// ---------- 256^2 double-buffered GEMM, SAFE schedule (full __syncthreads drain) ----------
#define MFMA_Q(H, G, BF) do { \
  __builtin_amdgcn_s_setprio(1); \
  _Pragma("unroll") \
  for (int mm = 0; mm < 4; ++mm) \
    _Pragma("unroll") \
    for (int nn = 0; nn < 2; ++nn) \
      _Pragma("unroll") \
      for (int ks = 0; ks < 2; ++ks) \
        acc[((H)<<2)+mm][((G)<<1)+nn] = __builtin_amdgcn_mfma_f32_16x16x32_bf16( \
            aF[mm][ks], BF[nn][ks], acc[((H)<<2)+mm][((G)<<1)+nn], 0, 0, 0); \
  __builtin_amdgcn_s_setprio(0); \
} while(0)

template<int EPI>
__global__ __launch_bounds__(512, 2)
void k_gemm256(const u16* __restrict__ A, const u16* __restrict__ BT,
               int Mt, int N, int K, int NT, long aBS, long btBS, int rowOffPerZ,
               float* __restrict__ X, const float* __restrict__ bias,
               u16* __restrict__ OUT){
  __shared__ __align__(16) u16 lds[2][2][256][64];   // [buf][A/B][row][col] = 128 KiB
  const int tid  = threadIdx.x;
  const int wave = tid >> 6, lane = tid & 63;
  const int wm = wave >> 2, wn = wave & 3;

  const int bz = blockIdx.z;
  const u16* Ab = A + (long)bz*aBS;
  const u16* Bb = BT + (long)bz*btBS;
  const int rowOff = bz*rowOffPerZ;

  // XCD-aware swizzle (nwg % 8 == 0 at all call sites)
  const int nwg = gridDim.x;
  const int id  = blockIdx.x;
  const int sw  = (id & 7) * (nwg >> 3) + (id >> 3);
  const int bm = (sw % Mt) << 8;
  const int bn = (sw / Mt) << 8;

  const int fr   = lane & 15;
  const int fks8 = (lane >> 4) << 3;
  const int swz  = (fr & 7) << 3;             // read-side XOR (elements)

  const int sRow = (wave << 3) + (lane >> 3); // staging row within half
  const int sCol = ((lane & 7) ^ ((lane >> 3) & 7)) << 3; // pre-swizzled src col chunk

  f32x4 acc[8][4] = {};
  bf16x8 aF[4][2], b0F[2][2], b1F[2][2];

  auto stage = [&](int tile){               // stage full tile (4 halves) into buf tile&1
    if (tile >= NT) return;
    #pragma unroll
    for (int h = 0; h < 4; ++h){
      const int isB   = ((h + 1) >> 1) & 1;
      const int rhalf = ((h >> 1) & 1) << 7;
      const u16* src = isB ? Bb : Ab;
      const int rb = (isB ? bn : bm) + rhalf + sRow;
      const u16* s0 = src + (long)rb * K + (tile << 6) + sCol;
      u16* d0 = &lds[tile & 1][isB][rhalf + (wave << 3)][0];
      __builtin_amdgcn_global_load_lds((__attribute__((address_space(1))) void*)(s0),
                                       (__attribute__((address_space(3))) void*)(d0), 16, 0, 0);
      __builtin_amdgcn_global_load_lds((__attribute__((address_space(1))) void*)(s0 + ((long)K << 6)),
                                       (__attribute__((address_space(3))) void*)(d0 + 64*64), 16, 0, 0);
    }
  };

  auto readA = [&](int c, int H){
    const u16* base = &lds[c][0][(H << 7) + (wm << 6)][0];
    #pragma unroll
    for (int mm = 0; mm < 4; ++mm)
      #pragma unroll
      for (int ks = 0; ks < 2; ++ks)
        aF[mm][ks] = *(const bf16x8*)&base[((mm<<4) + fr)*64 + (((ks<<5) + fks8) ^ swz)];
  };
  auto readB = [&](int c, int G, bf16x8 (&bF)[2][2]){
    const u16* base = &lds[c][1][(G << 7) + (wn << 5)][0];
    #pragma unroll
    for (int nn = 0; nn < 2; ++nn)
      #pragma unroll
      for (int ks = 0; ks < 2; ++ks)
        bF[nn][ks] = *(const bf16x8*)&base[((nn<<4) + fr)*64 + (((ks<<5) + fks8) ^ swz)];
  };

  stage(0);
  __syncthreads();                           // full drain: tile 0 resident

  int c = 0;
  for (int T = 0; T < NT; ++T, c ^= 1){
    stage(T + 1);                            // async into buf c^1, drained by end barrier
    readA(c, 0); readB(c, 0, b0F);
    MFMA_Q(0, 0, b0F);
    readB(c, 1, b1F);
    MFMA_Q(0, 1, b1F);
    readA(c, 1);
    MFMA_Q(1, 1, b1F);
    MFMA_Q(1, 0, b0F);
    __syncthreads();                         // drains vmcnt+lgkmcnt: T+1 resident, reads done
  }

  const int er = (lane >> 4) << 2, ec = lane & 15;
  #pragma unroll
  for (int mi = 0; mi < 8; ++mi){
    int row = bm + ((mi >> 2) << 7) + (wm << 6) + ((mi & 3) << 4) + er;
    #pragma unroll
    for (int ni = 0; ni < 4; ++ni){
      int col = bn + ((ni >> 1) << 7) + (wn << 5) + ((ni & 1) << 4) + ec;
      f32x4 v = acc[mi][ni];
      if constexpr (EPI == EPI_ADDX){
        float bv = bias ? bias[col] : 0.0f;
        #pragma unroll
        for (int r = 0; r < 4; r++)
          X[(long)(rowOff + row + r)*N + col] += v[r] + bv;
      } else if constexpr (EPI == EPI_GELU){
        float bv = bias[col];
        #pragma unroll
        for (int r = 0; r < 4; r++){
          float tt = v[r] + bv;
          OUT[(long)(row + r)*N + col] = f2bf(0.5f*tt*(1.0f + erff(tt*0.70710678118654752f)));
        }
      } else { // EPI_DFT: write transposed per batch into F[b][d][slot]
        int bb = row >> 11, s = row & 2047;
        int d, slot;
        if (col < 768){ d = col; slot = s; } else { d = col - 768; slot = 2048 + s; }
        u16x4 pk;
        #pragma unroll
        for (int r = 0; r < 4; r++) pk[r] = f2bf(v[r]);
        *(u16x4*)&OUT[((long)(bb*768 + d))*4096 + slot] = pk;
      }
    }
  }
}

__global__ void k_logits(const float* __restrict__ x, const float* __restrict__ Wout,
                         const float* __restrict__ bout, float* __restrict__ out){
  __shared__ float xl[8][768];
  int tid = threadIdx.x;
  for (int i = tid; i < 8*768; i += 256){
    int b = i/768, d = i - b*768;
    xl[b][d] = x[((long)(b*2048 + 2047))*768 + d];
  }
  __syncthreads();
  int v = blockIdx.x*256 + tid;
  float acc[8];
  float bv = bout[v];
  #pragma unroll
  for (int b = 0; b < 8; b++) acc[b] = bv;
  for (int d = 0; d < 768; d++){
    float w = Wout[(long)d*VOC + v];
    #pragma unroll
    for (int b = 0; b < 8; b++) acc[b] += xl[b][d]*w;
  }
  #pragma unroll
  for (int b = 0; b < 8; b++) out[(long)b*VOC + v] = acc[b];
}

extern "C" void kernel_launch(void* const* d_in, const int* in_sizes, int n_in,
                              void* d_out, int out_size, void* d_ws, size_t ws_size,
                              hipStream_t stream){
  const int*   tokens = (const int*)d_in[0];
  const float* embed  = (const float*)d_in[1];
  const float* ln1_g  = (const float*)d_in[2];
  const float* ln1_b  = (const float*)d_in[3];
  const float* ln2_g  = (const float*)d_in[4];
  const float* ln2_b  = (const float*)d_in[5];
  const float* W1     = (const float*)d_in[6];
  const float* b1     = (const float*)d_in[7];
  const float* W2     = (const float*)d_in[8];
  const float* b2     = (const float*)d_in[9];
  const float* Wout   = (const float*)d_in[10];
  const float* bout   = (const float*)d_in[11];
  float* out = (float*)d_out;

  char* p = (char*)d_ws;
  size_t off = 0;
  auto alloc = [&](size_t bytes)->char*{
    char* r = p + off; off += (bytes + 255) & ~(size_t)255; return r;
  };
  float* x   = (float*)alloc((size_t)ROWS*DD*4);     // f32 residual stream
  u16*   h   = (u16*)  alloc((size_t)ROWS*DD*2);     // LN output bf16
  u16*  gbuf = (u16*)  alloc((size_t)ROWS*DFF*2);    // MLP hidden; aliased as F
  u16*  dftD = (u16*)  alloc((size_t)1536*768*2);
  u16*  dftS = (u16*)  alloc((size_t)2048*4096*2);
  u16*  w1t  = (u16*)  alloc((size_t)DFF*DD*2);
  u16*  w2t  = (u16*)  alloc((size_t)DD*DFF*2);
  if (off > ws_size) return;
  u16* F = gbuf;

  k_dftD<<<(1536*768+255)/256, 256, 0, stream>>>(dftD);
  k_dftS<<<(2048*4096+255)/256, 256, 0, stream>>>(dftS);
  k_embed<<<(ROWS*192+255)/256, 256, 0, stream>>>(tokens, (const float4*)embed, (float4*)x);

  for (int l = 0; l < NL; l++){
    k_ln<<<ROWS/4, 256, 0, stream>>>(x, ln1_g + l*DD, ln1_b + l*DD, h);
    // yc|ys = h @ [C_D^T | S_D^T], written transposed into F  (M=16384,N=1536,K=768)
    k_gemm256<EPI_DFT><<<64*6, 512, 0, stream>>>(
        h, dftD, 64, 1536, 768, 12, 0, 0, 0, nullptr, nullptr, F);
    // x += [C_S | -S_S] @ [yc ; ys]  (M=2048,N=768,K=4096, batched over 8)
    k_gemm256<EPI_ADDX><<<dim3(8*3, 1, 8), 512, 0, stream>>>(
        dftS, F, 8, 768, 4096, 64, 0, (long)768*4096, 2048, x, nullptr, nullptr);
    k_ln<<<ROWS/4, 256, 0, stream>>>(x, ln2_g + l*DD, ln2_b + l*DD, h);
    k_transpose_cvt<<<dim3(DFF/32, DD/32), dim3(32,8), 0, stream>>>(
        W1 + (long)l*DD*DFF, w1t, DD, DFF);
    k_transpose_cvt<<<dim3(DD/32, DFF/32), dim3(32,8), 0, stream>>>(
        W2 + (long)l*DFF*DD, w2t, DFF, DD);
    // g = gelu(h @ W1 + b1)  (M=16384,N=3072,K=768)
    k_gemm256<EPI_GELU><<<64*12, 512, 0, stream>>>(
        h, w1t, 64, 3072, 768, 12, 0, 0, 0, nullptr, b1 + l*DFF, gbuf);
    // x += g @ W2 + b2  (M=16384,N=768,K=3072)
    k_gemm256<EPI_ADDX><<<64*3, 512, 0, stream>>>(
        gbuf, w2t, 64, 768, 3072, 48, 0, 0, 0, x, b2 + l*DD, nullptr);
  }
  k_logits<<<VOC/256, 256, 0, stream>>>(x, Wout, bout, out);
}